// Round 3
// baseline (346.775 us; speedup 1.0000x reference)
//
#include <hip/hip_runtime.h>
#include <hip/hip_bf16.h>
#include <hip/hip_fp16.h>

#define N_NODES 100000
#define N_EDGES 1600000
#define C 128
#define NB 782              // node buckets of 128: ceil(100000/128)
#define NC 256              // edge chunks
#define EPC (N_EDGES / NC)  // 6250 edges per chunk (exact)

typedef _Float16 half8 __attribute__((ext_vector_type(8)));
typedef _Float16 half4v __attribute__((ext_vector_type(4)));
typedef float f32x4 __attribute__((ext_vector_type(4)));

// ---------------- init: W pre-swizzle (blocks 0..15) + bucket count (rest) --
__global__ __launch_bounds__(256) void init_count(const float* __restrict__ W1,
                                                  const float* __restrict__ W2,
                                                  _Float16* __restrict__ W1s,
                                                  _Float16* __restrict__ W2s,
                                                  const int* __restrict__ dst,
                                                  int* __restrict__ cnt) {
    __shared__ int hist[NB];
    if (blockIdx.x < 16) {
        int i = blockIdx.x * 256 + threadIdx.x;   // 0..4095
        int which = i >> 11;
        int u = i & 2047;
        int lane = u & 63, l = lane & 15, q = lane >> 4;
        int ct = u >> 6, c = ct >> 3, t = ct & 7;
        const float* Wsrc = which ? W2 : W1;
        _Float16* Dst = which ? W2s : W1s;
        half8 v;
#pragma unroll
        for (int j = 0; j < 8; j++)
            v[j] = (_Float16)Wsrc[(c * 32 + q * 8 + j) * C + t * 16 + l];
        *(half8*)(Dst + (size_t)u * 8) = v;
    } else {
        int c = blockIdx.x - 16;                  // chunk 0..255
        int tid = threadIdx.x;
        for (int b = tid; b < NB; b += 256) hist[b] = 0;
        __syncthreads();
        int base = c * EPC;
        for (int i = tid; i < EPC; i += 256)
            atomicAdd(&hist[dst[base + i] >> 7], 1);
        __syncthreads();
        for (int b = tid; b < NB; b += 256) cnt[b * NC + c] = hist[b];
    }
}

// ---------------- generic exclusive scan over cnt (in place) ----------------
__global__ __launch_bounds__(256) void scan_block2(int* __restrict__ a,
                                                   int* __restrict__ partial, int n) {
    __shared__ int s[256];
    int tid = threadIdx.x;
    int i = blockIdx.x * 256 + tid;
    int v = (i < n) ? a[i] : 0;
    s[tid] = v;
    __syncthreads();
    for (int off = 1; off < 256; off <<= 1) {
        int t = (tid >= off) ? s[tid - off] : 0;
        __syncthreads();
        s[tid] += t;
        __syncthreads();
    }
    if (i < n) a[i] = s[tid] - v;                 // exclusive within block
    if (tid == 255) partial[blockIdx.x] = s[255];
}

__global__ __launch_bounds__(1024) void scan_partial_1024(int* __restrict__ partial, int n) {
    __shared__ int s[1024];
    int tid = threadIdx.x;
    int v = (tid < n) ? partial[tid] : 0;
    s[tid] = v;
    __syncthreads();
    for (int off = 1; off < 1024; off <<= 1) {
        int t = (tid >= off) ? s[tid - off] : 0;
        __syncthreads();
        s[tid] += t;
        __syncthreads();
    }
    if (tid < n) partial[tid] = s[tid] - v;
}

__global__ __launch_bounds__(256) void scan_add(int* __restrict__ a,
                                                const int* __restrict__ partial, int n) {
    int i = blockIdx.x * 256 + threadIdx.x;
    if (i < n) a[i] += partial[blockIdx.x];
}

// ---------------- GEMM compute+store phase (A already staged in smem) -------
__device__ __forceinline__ void gemm_compute_store(const _Float16* __restrict__ Wsw,
                                                   _Float16* __restrict__ out, int n,
                                                   int m0, int tid, _Float16* smem) {
    int lane = tid & 63;
    int w = tid >> 6;
    int l = lane & 15, q = lane >> 4;
    f32x4 acc[8] = {};

#pragma unroll
    for (int c = 0; c < 4; c++) {
        half8 af = *(const half8*)(smem + (w * 16 + l) * 128 + (((c * 4 + q) ^ l) * 8));
#pragma unroll
        for (int t = 0; t < 8; t++) {
            half8 bf = *(const half8*)(Wsw + (size_t)((c * 8 + t) * 64 + lane) * 8);
            acc[t] = __builtin_amdgcn_mfma_f32_16x16x32_f16(af, bf, acc[t], 0, 0, 0);
        }
    }

    __syncthreads();                       // all A reads done; reuse smem
    _Float16* cbuf = smem + w * 2176;      // [16][136] per wave
#pragma unroll
    for (int t = 0; t < 8; t++)
#pragma unroll
        for (int i = 0; i < 4; i++)        // C/D: col = t*16+l, row16 = q*4+i
            cbuf[(q * 4 + i) * 136 + t * 16 + l] = (_Float16)acc[t][i];
    __syncthreads();
#pragma unroll
    for (int i = 0; i < 4; i++) {
        int r16 = i * 4 + q;
        int row = m0 + w * 16 + r16;
        if (row < n)
            *(half8*)(out + (size_t)row * C + l * 8) =
                *(const half8*)(cbuf + r16 * 136 + l * 8);
    }
}

// ---------------- fused: gemm layer-1 (blocks < nbG) + bucket scatter -------
// Scatter writes 4B packed records ((dst&127)<<17 | src) into bucket order.
__global__ __launch_bounds__(256) void fused_gemm_scatter(const float* __restrict__ x,
                                                          const _Float16* __restrict__ W1s,
                                                          _Float16* __restrict__ h16, int n,
                                                          const int* __restrict__ src,
                                                          const int* __restrict__ dst,
                                                          const int* __restrict__ S,
                                                          unsigned int* __restrict__ bpacked,
                                                          int nbG) {
    __shared__ _Float16 smem[8704];
    if ((int)blockIdx.x < nbG) {
        int tid = threadIdx.x;
        int m0 = blockIdx.x * 64;
        const float4* A4 = (const float4*)x;
#pragma unroll
        for (int p = 0; p < 8; p++) {
            int idx = p * 256 + tid;
            int r = idx >> 5, f4 = idx & 31;
            int row = m0 + r; if (row >= n) row = n - 1;
            float4 v = A4[(size_t)row * 32 + f4];
            int kg = f4 >> 1, hi = f4 & 1;
            half4v hv = {(_Float16)v.x, (_Float16)v.y, (_Float16)v.z, (_Float16)v.w};
            *(half4v*)(smem + r * 128 + ((kg ^ (r & 15)) * 8) + hi * 4) = hv;
        }
        __syncthreads();
        gemm_compute_store(W1s, h16, n, m0, tid, smem);
    } else {
        int c = blockIdx.x - nbG;
        int tid = threadIdx.x;
        int* off = (int*)smem;                       // 782 ints, aliases gemm smem
        for (int b = tid; b < NB; b += 256) off[b] = S[b * NC + c];
        __syncthreads();
        int base = c * EPC;
        for (int i = tid; i < EPC; i += 256) {
            int s = src[base + i];
            int d = dst[base + i];
            int p = atomicAdd(&off[d >> 7], 1);      // LDS atomic
            bpacked[p] = ((unsigned int)(d & 127) << 17) | (unsigned int)s;
        }
    }
}

// ---------------- node sort: one block per bucket ---------------------------
// Packed bucket records -> node-sorted src list; emits rowptr, isq.
__global__ __launch_bounds__(256) void node_sort(const unsigned int* __restrict__ bpacked,
                                                 const int* __restrict__ S,
                                                 int* __restrict__ srcs,
                                                 int* __restrict__ rowptr,
                                                 float* __restrict__ isq) {
    __shared__ int hist[128];
    __shared__ int sc[128];
    __shared__ int off2[128];
    int b = blockIdx.x, tid = threadIdx.x;
    int beg = S[b * NC];
    int end = (b == NB - 1) ? N_EDGES : S[(b + 1) * NC];
    if (tid < 128) hist[tid] = 0;
    __syncthreads();
    for (int i = beg + tid; i < end; i += 256)
        atomicAdd(&hist[bpacked[i] >> 17], 1);
    __syncthreads();
    if (tid < 128) sc[tid] = hist[tid];
    __syncthreads();
    for (int off = 1; off < 128; off <<= 1) {
        int t = 0;
        if (tid < 128 && tid >= off) t = sc[tid - off];
        __syncthreads();
        if (tid < 128) sc[tid] += t;
        __syncthreads();
    }
    if (tid < 128) {
        int node = b * 128 + tid;
        int deg = hist[tid];
        int start = beg + sc[tid] - deg;             // exclusive scan
        off2[tid] = start;
        if (node < N_NODES) {
            rowptr[node] = start;
            isq[node] = rsqrtf((float)deg + 1.0f);   // +1: self-loop
        }
    }
    if (b == 0 && tid == 0) rowptr[N_NODES] = N_EDGES;
    __syncthreads();
    for (int i = beg + tid; i < end; i += 256) {
        unsigned int rec = bpacked[i];
        int li = (int)(rec >> 17);
        int p = atomicAdd(&off2[li], 1);             // LDS atomic
        srcs[p] = (int)(rec & 0x1FFFFu);
    }
}

// ---------------- fused: agg layer-1 + ReLU + GEMM layer-2 ------------------
// Block owns 64 nodes. Each wave aggregates its 16 nodes and writes the
// bias+ReLU'd fp16 rows straight into the swizzled GEMM A-tile (wave-private
// rows -> no barrier between agg and MFMA). Kills the hB16 HBM round-trip.
__global__ __launch_bounds__(256) void fused_agg_gemm(const _Float16* __restrict__ h,
                                                      const int* __restrict__ rowptr,
                                                      const int* __restrict__ srcs,
                                                      const float* __restrict__ isq,
                                                      const float* __restrict__ bias,
                                                      const _Float16* __restrict__ Wsw,
                                                      _Float16* __restrict__ out, int n) {
    __shared__ _Float16 smem[8704];
    int tid = threadIdx.x;
    int lane = tid & 63, w = tid >> 6;
    int q = lane >> 4, l16 = lane & 15;
    int cb = l16 * 8;
    int m0 = blockIdx.x * 64;

    float4 bv0 = *(const float4*)(bias + cb);
    float4 bv1 = *(const float4*)(bias + cb + 4);
    float bb[8] = {bv0.x, bv0.y, bv0.z, bv0.w, bv1.x, bv1.y, bv1.z, bv1.w};

#pragma unroll 1
    for (int t = 0; t < 16; t++) {
        int node = m0 + w * 16 + t;
        if (node >= n) node = n - 1;
        int beg = rowptr[node];
        int end = rowptr[node + 1];
        float iqd = isq[node];

        float acc[8] = {};
        int j = beg + q;
        for (; j + 12 < end; j += 16) {
            int s0 = srcs[j], s1 = srcs[j + 4], s2 = srcs[j + 8], s3 = srcs[j + 12];
            half8 h0 = *(const half8*)(h + (size_t)s0 * C + cb);
            half8 h1 = *(const half8*)(h + (size_t)s1 * C + cb);
            half8 h2 = *(const half8*)(h + (size_t)s2 * C + cb);
            half8 h3 = *(const half8*)(h + (size_t)s3 * C + cb);
            float c0 = isq[s0] * iqd;
            float c1 = isq[s1] * iqd;
            float c2 = isq[s2] * iqd;
            float c3 = isq[s3] * iqd;
#pragma unroll
            for (int k = 0; k < 8; k++) acc[k] += c0 * (float)h0[k];
#pragma unroll
            for (int k = 0; k < 8; k++) acc[k] += c1 * (float)h1[k];
#pragma unroll
            for (int k = 0; k < 8; k++) acc[k] += c2 * (float)h2[k];
#pragma unroll
            for (int k = 0; k < 8; k++) acc[k] += c3 * (float)h3[k];
        }
        for (; j < end; j += 4) {
            int s = srcs[j];
            half8 hv = *(const half8*)(h + (size_t)s * C + cb);
            float cf = isq[s] * iqd;
#pragma unroll
            for (int k = 0; k < 8; k++) acc[k] += cf * (float)hv[k];
        }

#pragma unroll
        for (int k = 0; k < 8; k++) {
            acc[k] += __shfl_xor(acc[k], 16, 64);
            acc[k] += __shfl_xor(acc[k], 32, 64);
        }

        if (q == 0) {
            float sc = iqd * iqd;                    // self-loop coef = 1/deg
            half8 hd = *(const half8*)(h + (size_t)node * C + cb);
            half8 o;
#pragma unroll
            for (int k = 0; k < 8; k++) {
                float vv = acc[k] + sc * (float)hd[k] + bb[k];
                o[k] = (_Float16)fmaxf(vv, 0.f);     // ReLU
            }
            int r = w * 16 + t;                      // r & 15 == t
            *(half8*)(smem + r * 128 + ((l16 ^ t) * 8)) = o;
        }
    }
    // A rows are wave-private (MFMA af reads row w*16+l only): no barrier here.
    gemm_compute_store(Wsw, out, n, m0, tid, smem);
}

// ---------------- layer-2 aggregation: one wave per dst node ----------------
template <bool RELU, typename OT>
__global__ __launch_bounds__(256) void aggregate(const _Float16* __restrict__ h,
                                                 const int* __restrict__ rowptr,
                                                 const int* __restrict__ srcs,
                                                 const float* __restrict__ isq,
                                                 const float* __restrict__ bias,
                                                 OT* __restrict__ out, int n) {
    int lane = threadIdx.x & 63;
    int wave = threadIdx.x >> 6;
    int node = blockIdx.x * 4 + wave;
    if (node >= n) return;

    int q   = lane >> 4;
    int l16 = lane & 15;
    int cb  = l16 * 8;

    int beg = rowptr[node];
    int end = rowptr[node + 1];
    float iqd = isq[node];

    float acc[8] = {};

    int j = beg + q;
    for (; j + 12 < end; j += 16) {
        int s0 = srcs[j], s1 = srcs[j + 4], s2 = srcs[j + 8], s3 = srcs[j + 12];
        half8 h0 = *(const half8*)(h + (size_t)s0 * C + cb);
        half8 h1 = *(const half8*)(h + (size_t)s1 * C + cb);
        half8 h2 = *(const half8*)(h + (size_t)s2 * C + cb);
        half8 h3 = *(const half8*)(h + (size_t)s3 * C + cb);
        float c0 = isq[s0] * iqd;
        float c1 = isq[s1] * iqd;
        float c2 = isq[s2] * iqd;
        float c3 = isq[s3] * iqd;
#pragma unroll
        for (int k = 0; k < 8; k++) acc[k] += c0 * (float)h0[k];
#pragma unroll
        for (int k = 0; k < 8; k++) acc[k] += c1 * (float)h1[k];
#pragma unroll
        for (int k = 0; k < 8; k++) acc[k] += c2 * (float)h2[k];
#pragma unroll
        for (int k = 0; k < 8; k++) acc[k] += c3 * (float)h3[k];
    }
    for (; j < end; j += 4) {
        int s = srcs[j];
        half8 hv = *(const half8*)(h + (size_t)s * C + cb);
        float cf = isq[s] * iqd;
#pragma unroll
        for (int k = 0; k < 8; k++) acc[k] += cf * (float)hv[k];
    }

#pragma unroll
    for (int k = 0; k < 8; k++) {
        acc[k] += __shfl_xor(acc[k], 16, 64);
        acc[k] += __shfl_xor(acc[k], 32, 64);
    }

    if (q == 0) {
        float sc = iqd * iqd;                       // self-loop coef = 1/deg
        half8 hd = *(const half8*)(h + (size_t)node * C + cb);
        float4 bv0 = *(const float4*)(bias + cb);
        float4 bv1 = *(const float4*)(bias + cb + 4);
        float bb[8] = {bv0.x, bv0.y, bv0.z, bv0.w, bv1.x, bv1.y, bv1.z, bv1.w};
#pragma unroll
        for (int k = 0; k < 8; k++) {
            acc[k] += sc * (float)hd[k] + bb[k];
            if (RELU) acc[k] = fmaxf(acc[k], 0.f);
        }
        if constexpr (sizeof(OT) == 2) {
            half8 o;
#pragma unroll
            for (int k = 0; k < 8; k++) o[k] = (_Float16)acc[k];
            *(half8*)((_Float16*)out + (size_t)node * C + cb) = o;
        } else {
            float4 o0 = {acc[0], acc[1], acc[2], acc[3]};
            float4 o1 = {acc[4], acc[5], acc[6], acc[7]};
            *(float4*)((float*)out + (size_t)node * C + cb) = o0;
            *(float4*)((float*)out + (size_t)node * C + cb + 4) = o1;
        }
    }
}

extern "C" void kernel_launch(void* const* d_in, const int* in_sizes, int n_in,
                              void* d_out, int out_size, void* d_ws, size_t ws_size,
                              hipStream_t stream) {
    const float* x  = (const float*)d_in[0];
    const int* ei   = (const int*)d_in[1];   // [2, E] int
    const float* W1 = (const float*)d_in[2];
    const float* b1 = (const float*)d_in[3];
    const float* W2 = (const float*)d_in[4];
    const float* b2 = (const float*)d_in[5];
    float* out = (float*)d_out;

    const int N = N_NODES, E = N_EDGES;
    const int* src = ei;
    const int* dst = ei + E;

    char* ws = (char*)d_ws;
    size_t off = 0;
    auto alloc = [&](size_t bytes) {
        size_t o = off;
        off = (off + bytes + 255) & ~(size_t)255;
        return o;
    };
    _Float16* h16   = (_Float16*)(ws + alloc((size_t)N * C * 2));  // gemm1 out / agg1 in
    _Float16* hB16  = (_Float16*)(ws + alloc((size_t)N * C * 2));  // fused agg+gemm2 out
    _Float16* W1s   = (_Float16*)(ws + alloc((size_t)C * C * 2));
    _Float16* W2s   = (_Float16*)(ws + alloc((size_t)C * C * 2));
    int*      cnt   = (int*)     (ws + alloc((size_t)NB * NC * 4)); // count/scan table
    int*      part  = (int*)     (ws + alloc((size_t)1024 * 4));
    unsigned int* bpacked = (unsigned int*)(ws + alloc((size_t)E * 4)); // bucket-sorted packed
    int*      srcs  = (int*)     (ws + alloc((size_t)E * 4));      // node-sorted src list
    int*    rowptr  = (int*)     (ws + alloc((size_t)(N + 1) * 4));
    float*    isq   = (float*)   (ws + alloc((size_t)N * 4));
    (void)ws_size; (void)n_in; (void)in_sizes; (void)out_size;

    const int nbG = (N + 63) / 64;     // 1563
    const int nS  = NB * NC;           // 200192
    const int nbS = nS / 256;          // 782 (exact)

    // 1: W swizzle + per-chunk bucket count (LDS histograms, no global atomics)
    init_count<<<16 + NC, 256, 0, stream>>>(W1, W2, W1s, W2s, dst, cnt);

    // 2-4: exclusive scan of cnt[bucket][chunk]
    scan_block2<<<nbS, 256, 0, stream>>>(cnt, part, nS);
    scan_partial_1024<<<1, 1024, 0, stream>>>(part, nbS);
    scan_add<<<nbS, 256, 0, stream>>>(cnt, part, nS);

    // 5: gemm layer-1 co-scheduled with 4B bucket scatter (LDS cursors)
    fused_gemm_scatter<<<nbG + NC, 256, 0, stream>>>(x, W1s, h16, N, src, dst, cnt,
                                                     bpacked, nbG);

    // 6: per-bucket node sort -> rowptr, isq, node-sorted srcs
    node_sort<<<NB, 256, 0, stream>>>(bpacked, cnt, srcs, rowptr, isq);

    // 7: fused layer-1 aggregation + ReLU + layer-2 GEMM (h16 -> hB16)
    fused_agg_gemm<<<nbG, 256, 0, stream>>>(h16, rowptr, srcs, isq, b1, W2s, hB16, N);

    // 8: layer-2 aggregation (fp32 out, +b2)
    aggregate<false, float><<<(N + 3) / 4, 256, 0, stream>>>(hB16, rowptr, srcs, isq, b2, out, N);
}

// Round 4
// 317.688 us; speedup vs baseline: 1.0916x; 1.0916x over previous
//
#include <hip/hip_runtime.h>
#include <hip/hip_bf16.h>
#include <hip/hip_fp16.h>

#define N_NODES 100000
#define N_EDGES 1600000
#define C 128
#define NB 782              // node buckets of 128: ceil(100000/128)
#define NC 256              // edge chunks (== scan block size; scan_add folds away)
#define EPC (N_EDGES / NC)  // 6250 edges per chunk (exact)

typedef _Float16 half8 __attribute__((ext_vector_type(8)));
typedef _Float16 half4v __attribute__((ext_vector_type(4)));
typedef float f32x4 __attribute__((ext_vector_type(4)));

// ---------------- init: W pre-swizzle (blocks 0..15) + bucket count (rest) --
__global__ __launch_bounds__(256) void init_count(const float* __restrict__ W1,
                                                  const float* __restrict__ W2,
                                                  _Float16* __restrict__ W1s,
                                                  _Float16* __restrict__ W2s,
                                                  const int* __restrict__ dst,
                                                  int* __restrict__ cnt) {
    __shared__ int hist[NB];
    if (blockIdx.x < 16) {
        int i = blockIdx.x * 256 + threadIdx.x;   // 0..4095
        int which = i >> 11;
        int u = i & 2047;
        int lane = u & 63, l = lane & 15, q = lane >> 4;
        int ct = u >> 6, c = ct >> 3, t = ct & 7;
        const float* Wsrc = which ? W2 : W1;
        _Float16* Dst = which ? W2s : W1s;
        half8 v;
#pragma unroll
        for (int j = 0; j < 8; j++)
            v[j] = (_Float16)Wsrc[(c * 32 + q * 8 + j) * C + t * 16 + l];
        *(half8*)(Dst + (size_t)u * 8) = v;
    } else {
        int c = blockIdx.x - 16;                  // chunk 0..255
        int tid = threadIdx.x;
        for (int b = tid; b < NB; b += 256) hist[b] = 0;
        __syncthreads();
        int base = c * EPC;
        for (int i = tid; i < EPC; i += 256)
            atomicAdd(&hist[dst[base + i] >> 7], 1);
        __syncthreads();
        for (int b = tid; b < NB; b += 256) cnt[b * NC + c] = hist[b];
    }
}

// ---------------- scan: within-bucket over chunks + bucket totals -----------
// NC == 256 == block size, so scan block b covers exactly bucket b:
// after these two kernels, global_off(b,c) = cnt[b*NC+c] + part[b], and
// bucket b's edge range is [part[b], part[b+1]).
__global__ __launch_bounds__(256) void scan_block2(int* __restrict__ a,
                                                   int* __restrict__ partial, int n) {
    __shared__ int s[256];
    int tid = threadIdx.x;
    int i = blockIdx.x * 256 + tid;
    int v = (i < n) ? a[i] : 0;
    s[tid] = v;
    __syncthreads();
    for (int off = 1; off < 256; off <<= 1) {
        int t = (tid >= off) ? s[tid - off] : 0;
        __syncthreads();
        s[tid] += t;
        __syncthreads();
    }
    if (i < n) a[i] = s[tid] - v;                 // exclusive within bucket
    if (tid == 255) partial[blockIdx.x] = s[255];
}

__global__ __launch_bounds__(1024) void scan_partial_1024(int* __restrict__ partial, int n) {
    __shared__ int s[1024];
    int tid = threadIdx.x;
    int v = (tid < n) ? partial[tid] : 0;
    s[tid] = v;
    __syncthreads();
    for (int off = 1; off < 1024; off <<= 1) {
        int t = (tid >= off) ? s[tid - off] : 0;
        __syncthreads();
        s[tid] += t;
        __syncthreads();
    }
    if (tid < n) partial[tid] = s[tid] - v;
}

// ---------------- GEMM compute+store phase (A already staged in smem) -------
__device__ __forceinline__ void gemm_compute_store(const _Float16* __restrict__ Wsw,
                                                   _Float16* __restrict__ out, int n,
                                                   int m0, int tid, _Float16* smem) {
    int lane = tid & 63;
    int w = tid >> 6;
    int l = lane & 15, q = lane >> 4;
    f32x4 acc[8] = {};

#pragma unroll
    for (int c = 0; c < 4; c++) {
        half8 af = *(const half8*)(smem + (w * 16 + l) * 128 + (((c * 4 + q) ^ l) * 8));
#pragma unroll
        for (int t = 0; t < 8; t++) {
            half8 bf = *(const half8*)(Wsw + (size_t)((c * 8 + t) * 64 + lane) * 8);
            acc[t] = __builtin_amdgcn_mfma_f32_16x16x32_f16(af, bf, acc[t], 0, 0, 0);
        }
    }

    __syncthreads();                       // all A reads done; reuse smem
    _Float16* cbuf = smem + w * 2176;      // [16][136] per wave
#pragma unroll
    for (int t = 0; t < 8; t++)
#pragma unroll
        for (int i = 0; i < 4; i++)        // C/D: col = t*16+l, row16 = q*4+i
            cbuf[(q * 4 + i) * 136 + t * 16 + l] = (_Float16)acc[t][i];
    __syncthreads();
#pragma unroll
    for (int i = 0; i < 4; i++) {
        int r16 = i * 4 + q;
        int row = m0 + w * 16 + r16;
        if (row < n)
            *(half8*)(out + (size_t)row * C + l * 8) =
                *(const half8*)(cbuf + r16 * 136 + l * 8);
    }
}

// ---------------- fused: gemm layer-1 (blocks < nbG) + bucket scatter -------
// Scatter writes 4B packed records ((dst&127)<<17 | src) into bucket order.
__global__ __launch_bounds__(256) void fused_gemm_scatter(const float* __restrict__ x,
                                                          const _Float16* __restrict__ W1s,
                                                          _Float16* __restrict__ h16, int n,
                                                          const int* __restrict__ src,
                                                          const int* __restrict__ dst,
                                                          const int* __restrict__ S,
                                                          const int* __restrict__ part,
                                                          unsigned int* __restrict__ bpacked,
                                                          int nbG) {
    __shared__ _Float16 smem[8704];
    if ((int)blockIdx.x < nbG) {
        int tid = threadIdx.x;
        int m0 = blockIdx.x * 64;
        const float4* A4 = (const float4*)x;
#pragma unroll
        for (int p = 0; p < 8; p++) {
            int idx = p * 256 + tid;
            int r = idx >> 5, f4 = idx & 31;
            int row = m0 + r; if (row >= n) row = n - 1;
            float4 v = A4[(size_t)row * 32 + f4];
            int kg = f4 >> 1, hi = f4 & 1;
            half4v hv = {(_Float16)v.x, (_Float16)v.y, (_Float16)v.z, (_Float16)v.w};
            *(half4v*)(smem + r * 128 + ((kg ^ (r & 15)) * 8) + hi * 4) = hv;
        }
        __syncthreads();
        gemm_compute_store(W1s, h16, n, m0, tid, smem);
    } else {
        int c = blockIdx.x - nbG;
        int tid = threadIdx.x;
        int* off = (int*)smem;                       // 782 ints, aliases gemm smem
        for (int b = tid; b < NB; b += 256) off[b] = S[b * NC + c] + part[b];
        __syncthreads();
        int base = c * EPC;
        for (int i = tid; i < EPC; i += 256) {
            int s = src[base + i];
            int d = dst[base + i];
            int p = atomicAdd(&off[d >> 7], 1);      // LDS atomic
            bpacked[p] = ((unsigned int)(d & 127) << 17) | (unsigned int)s;
        }
    }
}

// ---------------- node sort: one block per bucket ---------------------------
// Packed bucket records -> node-sorted src list; emits rowptr, isq.
__global__ __launch_bounds__(256) void node_sort(const unsigned int* __restrict__ bpacked,
                                                 const int* __restrict__ part,
                                                 int* __restrict__ srcs,
                                                 int* __restrict__ rowptr,
                                                 float* __restrict__ isq) {
    __shared__ int hist[128];
    __shared__ int sc[128];
    __shared__ int off2[128];
    int b = blockIdx.x, tid = threadIdx.x;
    int beg = part[b];
    int end = (b == NB - 1) ? N_EDGES : part[b + 1];
    if (tid < 128) hist[tid] = 0;
    __syncthreads();
    for (int i = beg + tid; i < end; i += 256)
        atomicAdd(&hist[bpacked[i] >> 17], 1);
    __syncthreads();
    if (tid < 128) sc[tid] = hist[tid];
    __syncthreads();
    for (int off = 1; off < 128; off <<= 1) {
        int t = 0;
        if (tid < 128 && tid >= off) t = sc[tid - off];
        __syncthreads();
        if (tid < 128) sc[tid] += t;
        __syncthreads();
    }
    if (tid < 128) {
        int node = b * 128 + tid;
        int deg = hist[tid];
        int start = beg + sc[tid] - deg;             // exclusive scan
        off2[tid] = start;
        if (node < N_NODES) {
            rowptr[node] = start;
            isq[node] = rsqrtf((float)deg + 1.0f);   // +1: self-loop
        }
    }
    if (b == 0 && tid == 0) rowptr[N_NODES] = N_EDGES;
    __syncthreads();
    for (int i = beg + tid; i < end; i += 256) {
        unsigned int rec = bpacked[i];
        int li = (int)(rec >> 17);
        int p = atomicAdd(&off2[li], 1);             // LDS atomic
        srcs[p] = (int)(rec & 0x1FFFFu);
    }
}

// ---------------- layer-2 GEMM (fp16 in, standalone) ------------------------
__global__ __launch_bounds__(256) void gemm_mfma(const _Float16* __restrict__ A,
                                                 const _Float16* __restrict__ Wsw,
                                                 _Float16* __restrict__ out, int n) {
    __shared__ _Float16 smem[8704];
    int tid = threadIdx.x;
    int m0 = blockIdx.x * 64;
#pragma unroll
    for (int p = 0; p < 4; p++) {
        int idx = p * 256 + tid;
        int r = idx >> 4, kg = idx & 15;
        int row = m0 + r; if (row >= n) row = n - 1;
        half8 v = *(const half8*)(A + (size_t)row * C + kg * 8);
        *(half8*)(smem + r * 128 + ((kg ^ (r & 15)) * 8)) = v;
    }
    __syncthreads();
    gemm_compute_store(Wsw, out, n, m0, tid, smem);
}

// ---------------- aggregation: one 16-lane q-group per dst node -------------
// Mean degree is 16, so the old node-per-wave loop (16 edges/iter) never
// filled. Here each q-group owns a node: 16 lanes x 16B = one full 256B row
// per edge, 4-deep unroll -> 16 independent row-gathers in flight per wave,
// no cross-lane reduce, no q==0 serialization. Grid covers n exactly.
template <bool RELU, typename OT>
__global__ __launch_bounds__(256) void aggregate(const _Float16* __restrict__ h,
                                                 const int* __restrict__ rowptr,
                                                 const int* __restrict__ srcs,
                                                 const float* __restrict__ isq,
                                                 const float* __restrict__ bias,
                                                 OT* __restrict__ out, int n) {
    int lane = threadIdx.x & 63;
    int wave = threadIdx.x >> 6;
    int q = lane >> 4;
    int l16 = lane & 15;
    int cb = l16 * 8;
    int node = blockIdx.x * 16 + wave * 4 + q;   // grid*16 == n exactly

    int beg = rowptr[node];
    int end = rowptr[node + 1];
    float iqd = isq[node];

    float acc[8] = {};
    int j = beg;
    for (; j + 3 < end; j += 4) {
        int s0 = srcs[j], s1 = srcs[j + 1], s2 = srcs[j + 2], s3 = srcs[j + 3];
        half8 h0 = *(const half8*)(h + (size_t)s0 * C + cb);
        half8 h1 = *(const half8*)(h + (size_t)s1 * C + cb);
        half8 h2 = *(const half8*)(h + (size_t)s2 * C + cb);
        half8 h3 = *(const half8*)(h + (size_t)s3 * C + cb);
        float c0 = isq[s0] * iqd;
        float c1 = isq[s1] * iqd;
        float c2 = isq[s2] * iqd;
        float c3 = isq[s3] * iqd;
#pragma unroll
        for (int k = 0; k < 8; k++) acc[k] += c0 * (float)h0[k];
#pragma unroll
        for (int k = 0; k < 8; k++) acc[k] += c1 * (float)h1[k];
#pragma unroll
        for (int k = 0; k < 8; k++) acc[k] += c2 * (float)h2[k];
#pragma unroll
        for (int k = 0; k < 8; k++) acc[k] += c3 * (float)h3[k];
    }
    for (; j < end; ++j) {
        int s = srcs[j];
        half8 hv = *(const half8*)(h + (size_t)s * C + cb);
        float cf = isq[s] * iqd;
#pragma unroll
        for (int k = 0; k < 8; k++) acc[k] += cf * (float)hv[k];
    }

    // self-loop + bias (+ReLU); every q-group finalizes its own node
    float sc = iqd * iqd;
    half8 hd = *(const half8*)(h + (size_t)node * C + cb);
    float4 bv0 = *(const float4*)(bias + cb);
    float4 bv1 = *(const float4*)(bias + cb + 4);
    float bb[8] = {bv0.x, bv0.y, bv0.z, bv0.w, bv1.x, bv1.y, bv1.z, bv1.w};
#pragma unroll
    for (int k = 0; k < 8; k++) {
        acc[k] += sc * (float)hd[k] + bb[k];
        if (RELU) acc[k] = fmaxf(acc[k], 0.f);
    }
    if constexpr (sizeof(OT) == 2) {
        half8 o;
#pragma unroll
        for (int k = 0; k < 8; k++) o[k] = (_Float16)acc[k];
        *(half8*)((_Float16*)out + (size_t)node * C + cb) = o;
    } else {
        float4 o0 = {acc[0], acc[1], acc[2], acc[3]};
        float4 o1 = {acc[4], acc[5], acc[6], acc[7]};
        *(float4*)((float*)out + (size_t)node * C + cb) = o0;
        *(float4*)((float*)out + (size_t)node * C + cb + 4) = o1;
    }
}

extern "C" void kernel_launch(void* const* d_in, const int* in_sizes, int n_in,
                              void* d_out, int out_size, void* d_ws, size_t ws_size,
                              hipStream_t stream) {
    const float* x  = (const float*)d_in[0];
    const int* ei   = (const int*)d_in[1];   // [2, E] int
    const float* W1 = (const float*)d_in[2];
    const float* b1 = (const float*)d_in[3];
    const float* W2 = (const float*)d_in[4];
    const float* b2 = (const float*)d_in[5];
    float* out = (float*)d_out;

    const int N = N_NODES, E = N_EDGES;
    const int* src = ei;
    const int* dst = ei + E;

    char* ws = (char*)d_ws;
    size_t off = 0;
    auto alloc = [&](size_t bytes) {
        size_t o = off;
        off = (off + bytes + 255) & ~(size_t)255;
        return o;
    };
    _Float16* h16   = (_Float16*)(ws + alloc((size_t)N * C * 2));  // gemm1 out / agg1 in
    _Float16* hB16  = (_Float16*)(ws + alloc((size_t)N * C * 2));  // agg1 out / gemm2 in
    _Float16* hC16  = (_Float16*)(ws + alloc((size_t)N * C * 2));  // gemm2 out / agg2 in
    _Float16* W1s   = (_Float16*)(ws + alloc((size_t)C * C * 2));
    _Float16* W2s   = (_Float16*)(ws + alloc((size_t)C * C * 2));
    int*      cnt   = (int*)     (ws + alloc((size_t)NB * NC * 4)); // count/scan table
    int*      part  = (int*)     (ws + alloc((size_t)1024 * 4));
    unsigned int* bpacked = (unsigned int*)(ws + alloc((size_t)E * 4)); // bucket-sorted packed
    int*      srcs  = (int*)     (ws + alloc((size_t)E * 4));      // node-sorted src list
    int*    rowptr  = (int*)     (ws + alloc((size_t)(N + 1) * 4));
    float*    isq   = (float*)   (ws + alloc((size_t)N * 4));
    (void)ws_size; (void)n_in; (void)in_sizes; (void)out_size;

    const int nbG = (N + 63) / 64;     // 1563
    const int nS  = NB * NC;           // 200192
    const int nbS = nS / 256;          // 782 (exact; block b == bucket b)
    const int nbA = N / 16;            // 6250 (exact: 6250*16 == 100000)

    // 1: W swizzle + per-chunk bucket count (LDS histograms, no global atomics)
    init_count<<<16 + NC, 256, 0, stream>>>(W1, W2, W1s, W2s, dst, cnt);

    // 2-3: within-bucket exclusive scan + bucket-total scan (scan_add folded)
    scan_block2<<<nbS, 256, 0, stream>>>(cnt, part, nS);
    scan_partial_1024<<<1, 1024, 0, stream>>>(part, nbS);

    // 4: gemm layer-1 co-scheduled with 4B bucket scatter (LDS cursors)
    fused_gemm_scatter<<<nbG + NC, 256, 0, stream>>>(x, W1s, h16, N, src, dst, cnt,
                                                     part, bpacked, nbG);

    // 5: per-bucket node sort -> rowptr, isq, node-sorted srcs
    node_sort<<<NB, 256, 0, stream>>>(bpacked, part, srcs, rowptr, isq);

    // 6: layer-1 aggregation + ReLU (fp16 out)
    aggregate<true, _Float16><<<nbA, 256, 0, stream>>>(h16, rowptr, srcs, isq, b1, hB16, N);

    // 7: layer-2 GEMM
    gemm_mfma<<<nbG, 256, 0, stream>>>(hB16, W2s, hC16, N);

    // 8: layer-2 aggregation (fp32 out, +b2)
    aggregate<false, float><<<nbA, 256, 0, stream>>>(hC16, rowptr, srcs, isq, b2, out, N);
}

// Round 5
// 312.119 us; speedup vs baseline: 1.1110x; 1.0178x over previous
//
#include <hip/hip_runtime.h>
#include <hip/hip_bf16.h>
#include <hip/hip_fp16.h>

#define N_NODES 100000
#define N_EDGES 1600000
#define C 128
#define NB 782              // node buckets of 128: ceil(100000/128)
#define NC 1024             // edge chunks (== scan_block2 block size; scan_add folds away)
#define EPC 1563            // ceil(N_EDGES / NC); last chunk ragged

typedef _Float16 half8 __attribute__((ext_vector_type(8)));
typedef _Float16 half4v __attribute__((ext_vector_type(4)));
typedef float f32x4 __attribute__((ext_vector_type(4)));

// ---------------- init: W pre-swizzle (blocks 0..15) + bucket count (rest) --
__global__ __launch_bounds__(256) void init_count(const float* __restrict__ W1,
                                                  const float* __restrict__ W2,
                                                  _Float16* __restrict__ W1s,
                                                  _Float16* __restrict__ W2s,
                                                  const int* __restrict__ dst,
                                                  int* __restrict__ cnt) {
    __shared__ int hist[NB];
    if (blockIdx.x < 16) {
        int i = blockIdx.x * 256 + threadIdx.x;   // 0..4095
        int which = i >> 11;
        int u = i & 2047;
        int lane = u & 63, l = lane & 15, q = lane >> 4;
        int ct = u >> 6, c = ct >> 3, t = ct & 7;
        const float* Wsrc = which ? W2 : W1;
        _Float16* Dst = which ? W2s : W1s;
        half8 v;
#pragma unroll
        for (int j = 0; j < 8; j++)
            v[j] = (_Float16)Wsrc[(c * 32 + q * 8 + j) * C + t * 16 + l];
        *(half8*)(Dst + (size_t)u * 8) = v;
    } else {
        int c = blockIdx.x - 16;                  // chunk 0..NC-1
        int tid = threadIdx.x;
        for (int b = tid; b < NB; b += 256) hist[b] = 0;
        __syncthreads();
        int base = c * EPC;
        int cend = base + EPC; if (cend > N_EDGES) cend = N_EDGES;
        for (int i = base + tid; i < cend; i += 256)
            atomicAdd(&hist[dst[i] >> 7], 1);
        __syncthreads();
        for (int b = tid; b < NB; b += 256) cnt[b * NC + c] = hist[b];
    }
}

// ---------------- scan: within-bucket over chunks + bucket totals -----------
// NC == 1024 == block size, so scan block b covers exactly bucket b:
// after these two kernels, global_off(b,c) = cnt[b*NC+c] + part[b], and
// bucket b's edge range is [part[b], part[b+1]).
__global__ __launch_bounds__(1024) void scan_block2(int* __restrict__ a,
                                                    int* __restrict__ partial, int n) {
    __shared__ int s[1024];
    int tid = threadIdx.x;
    int i = blockIdx.x * 1024 + tid;
    int v = (i < n) ? a[i] : 0;
    s[tid] = v;
    __syncthreads();
    for (int off = 1; off < 1024; off <<= 1) {
        int t = (tid >= off) ? s[tid - off] : 0;
        __syncthreads();
        s[tid] += t;
        __syncthreads();
    }
    if (i < n) a[i] = s[tid] - v;                 // exclusive within bucket
    if (tid == 1023) partial[blockIdx.x] = s[1023];
}

__global__ __launch_bounds__(1024) void scan_partial_1024(int* __restrict__ partial, int n) {
    __shared__ int s[1024];
    int tid = threadIdx.x;
    int v = (tid < n) ? partial[tid] : 0;
    s[tid] = v;
    __syncthreads();
    for (int off = 1; off < 1024; off <<= 1) {
        int t = (tid >= off) ? s[tid - off] : 0;
        __syncthreads();
        s[tid] += t;
        __syncthreads();
    }
    if (tid < n) partial[tid] = s[tid] - v;
}

// ---------------- GEMM compute+store phase (A already staged in smem) -------
__device__ __forceinline__ void gemm_compute_store(const _Float16* __restrict__ Wsw,
                                                   _Float16* __restrict__ out, int n,
                                                   int m0, int tid, _Float16* smem) {
    int lane = tid & 63;
    int w = tid >> 6;
    int l = lane & 15, q = lane >> 4;
    f32x4 acc[8] = {};

#pragma unroll
    for (int c = 0; c < 4; c++) {
        half8 af = *(const half8*)(smem + (w * 16 + l) * 128 + (((c * 4 + q) ^ l) * 8));
#pragma unroll
        for (int t = 0; t < 8; t++) {
            half8 bf = *(const half8*)(Wsw + (size_t)((c * 8 + t) * 64 + lane) * 8);
            acc[t] = __builtin_amdgcn_mfma_f32_16x16x32_f16(af, bf, acc[t], 0, 0, 0);
        }
    }

    __syncthreads();                       // all A reads done; reuse smem
    _Float16* cbuf = smem + w * 2176;      // [16][136] per wave
#pragma unroll
    for (int t = 0; t < 8; t++)
#pragma unroll
        for (int i = 0; i < 4; i++)        // C/D: col = t*16+l, row16 = q*4+i
            cbuf[(q * 4 + i) * 136 + t * 16 + l] = (_Float16)acc[t][i];
    __syncthreads();
#pragma unroll
    for (int i = 0; i < 4; i++) {
        int r16 = i * 4 + q;
        int row = m0 + w * 16 + r16;
        if (row < n)
            *(half8*)(out + (size_t)row * C + l * 8) =
                *(const half8*)(cbuf + r16 * 136 + l * 8);
    }
}

// ---------------- fused: gemm layer-1 (blocks < nbG) + bucket scatter -------
// Scatter writes 4B packed records ((dst&127)<<17 | src) into bucket order.
// NC=1024 chunks -> ~4 scatter blocks/CU stay resident after GEMM drains.
__global__ __launch_bounds__(256) void fused_gemm_scatter(const float* __restrict__ x,
                                                          const _Float16* __restrict__ W1s,
                                                          _Float16* __restrict__ h16, int n,
                                                          const int* __restrict__ src,
                                                          const int* __restrict__ dst,
                                                          const int* __restrict__ S,
                                                          const int* __restrict__ part,
                                                          unsigned int* __restrict__ bpacked,
                                                          int nbG) {
    __shared__ _Float16 smem[8704];
    if ((int)blockIdx.x < nbG) {
        int tid = threadIdx.x;
        int m0 = blockIdx.x * 64;
        const float4* A4 = (const float4*)x;
#pragma unroll
        for (int p = 0; p < 8; p++) {
            int idx = p * 256 + tid;
            int r = idx >> 5, f4 = idx & 31;
            int row = m0 + r; if (row >= n) row = n - 1;
            float4 v = A4[(size_t)row * 32 + f4];
            int kg = f4 >> 1, hi = f4 & 1;
            half4v hv = {(_Float16)v.x, (_Float16)v.y, (_Float16)v.z, (_Float16)v.w};
            *(half4v*)(smem + r * 128 + ((kg ^ (r & 15)) * 8) + hi * 4) = hv;
        }
        __syncthreads();
        gemm_compute_store(W1s, h16, n, m0, tid, smem);
    } else {
        int c = blockIdx.x - nbG;
        int tid = threadIdx.x;
        int* off = (int*)smem;                       // 782 ints, aliases gemm smem
        for (int b = tid; b < NB; b += 256) off[b] = S[b * NC + c] + part[b];
        __syncthreads();
        int base = c * EPC;
        int cend = base + EPC; if (cend > N_EDGES) cend = N_EDGES;
        for (int i = base + tid; i < cend; i += 256) {
            int s = src[i];
            int d = dst[i];
            int p = atomicAdd(&off[d >> 7], 1);      // LDS atomic
            bpacked[p] = ((unsigned int)(d & 127) << 17) | (unsigned int)s;
        }
    }
}

// ---------------- node sort: one block per bucket ---------------------------
// Packed bucket records -> node-sorted src list; emits rowptr, isq.
__global__ __launch_bounds__(256) void node_sort(const unsigned int* __restrict__ bpacked,
                                                 const int* __restrict__ part,
                                                 int* __restrict__ srcs,
                                                 int* __restrict__ rowptr,
                                                 float* __restrict__ isq) {
    __shared__ int hist[128];
    __shared__ int sc[128];
    __shared__ int off2[128];
    int b = blockIdx.x, tid = threadIdx.x;
    int beg = part[b];
    int end = (b == NB - 1) ? N_EDGES : part[b + 1];
    if (tid < 128) hist[tid] = 0;
    __syncthreads();
    for (int i = beg + tid; i < end; i += 256)
        atomicAdd(&hist[bpacked[i] >> 17], 1);
    __syncthreads();
    if (tid < 128) sc[tid] = hist[tid];
    __syncthreads();
    for (int off = 1; off < 128; off <<= 1) {
        int t = 0;
        if (tid < 128 && tid >= off) t = sc[tid - off];
        __syncthreads();
        if (tid < 128) sc[tid] += t;
        __syncthreads();
    }
    if (tid < 128) {
        int node = b * 128 + tid;
        int deg = hist[tid];
        int start = beg + sc[tid] - deg;             // exclusive scan
        off2[tid] = start;
        if (node < N_NODES) {
            rowptr[node] = start;
            isq[node] = rsqrtf((float)deg + 1.0f);   // +1: self-loop
        }
    }
    if (b == 0 && tid == 0) rowptr[N_NODES] = N_EDGES;
    __syncthreads();
    for (int i = beg + tid; i < end; i += 256) {
        unsigned int rec = bpacked[i];
        int li = (int)(rec >> 17);
        int p = atomicAdd(&off2[li], 1);             // LDS atomic
        srcs[p] = (int)(rec & 0x1FFFFu);
    }
}

// ---------------- layer-2 GEMM (fp16 in, standalone) ------------------------
__global__ __launch_bounds__(256) void gemm_mfma(const _Float16* __restrict__ A,
                                                 const _Float16* __restrict__ Wsw,
                                                 _Float16* __restrict__ out, int n) {
    __shared__ _Float16 smem[8704];
    int tid = threadIdx.x;
    int m0 = blockIdx.x * 64;
#pragma unroll
    for (int p = 0; p < 4; p++) {
        int idx = p * 256 + tid;
        int r = idx >> 4, kg = idx & 15;
        int row = m0 + r; if (row >= n) row = n - 1;
        half8 v = *(const half8*)(A + (size_t)row * C + kg * 8);
        *(half8*)(smem + r * 128 + ((kg ^ (r & 15)) * 8)) = v;
    }
    __syncthreads();
    gemm_compute_store(Wsw, out, n, m0, tid, smem);
}

// ---------------- aggregation: one 16-lane q-group per dst node -------------
template <bool RELU, typename OT>
__global__ __launch_bounds__(256) void aggregate(const _Float16* __restrict__ h,
                                                 const int* __restrict__ rowptr,
                                                 const int* __restrict__ srcs,
                                                 const float* __restrict__ isq,
                                                 const float* __restrict__ bias,
                                                 OT* __restrict__ out, int n) {
    int lane = threadIdx.x & 63;
    int wave = threadIdx.x >> 6;
    int q = lane >> 4;
    int l16 = lane & 15;
    int cb = l16 * 8;
    int node = blockIdx.x * 16 + wave * 4 + q;   // grid*16 == n exactly

    int beg = rowptr[node];
    int end = rowptr[node + 1];
    float iqd = isq[node];

    float acc[8] = {};
    int j = beg;
    for (; j + 3 < end; j += 4) {
        int s0 = srcs[j], s1 = srcs[j + 1], s2 = srcs[j + 2], s3 = srcs[j + 3];
        half8 h0 = *(const half8*)(h + (size_t)s0 * C + cb);
        half8 h1 = *(const half8*)(h + (size_t)s1 * C + cb);
        half8 h2 = *(const half8*)(h + (size_t)s2 * C + cb);
        half8 h3 = *(const half8*)(h + (size_t)s3 * C + cb);
        float c0 = isq[s0] * iqd;
        float c1 = isq[s1] * iqd;
        float c2 = isq[s2] * iqd;
        float c3 = isq[s3] * iqd;
#pragma unroll
        for (int k = 0; k < 8; k++) acc[k] += c0 * (float)h0[k];
#pragma unroll
        for (int k = 0; k < 8; k++) acc[k] += c1 * (float)h1[k];
#pragma unroll
        for (int k = 0; k < 8; k++) acc[k] += c2 * (float)h2[k];
#pragma unroll
        for (int k = 0; k < 8; k++) acc[k] += c3 * (float)h3[k];
    }
    for (; j < end; ++j) {
        int s = srcs[j];
        half8 hv = *(const half8*)(h + (size_t)s * C + cb);
        float cf = isq[s] * iqd;
#pragma unroll
        for (int k = 0; k < 8; k++) acc[k] += cf * (float)hv[k];
    }

    // self-loop + bias (+ReLU); every q-group finalizes its own node
    float sc = iqd * iqd;
    half8 hd = *(const half8*)(h + (size_t)node * C + cb);
    float4 bv0 = *(const float4*)(bias + cb);
    float4 bv1 = *(const float4*)(bias + cb + 4);
    float bb[8] = {bv0.x, bv0.y, bv0.z, bv0.w, bv1.x, bv1.y, bv1.z, bv1.w};
#pragma unroll
    for (int k = 0; k < 8; k++) {
        acc[k] += sc * (float)hd[k] + bb[k];
        if (RELU) acc[k] = fmaxf(acc[k], 0.f);
    }
    if constexpr (sizeof(OT) == 2) {
        half8 o;
#pragma unroll
        for (int k = 0; k < 8; k++) o[k] = (_Float16)acc[k];
        *(half8*)((_Float16*)out + (size_t)node * C + cb) = o;
    } else {
        float4 o0 = {acc[0], acc[1], acc[2], acc[3]};
        float4 o1 = {acc[4], acc[5], acc[6], acc[7]};
        *(float4*)((float*)out + (size_t)node * C + cb) = o0;
        *(float4*)((float*)out + (size_t)node * C + cb + 4) = o1;
    }
}

extern "C" void kernel_launch(void* const* d_in, const int* in_sizes, int n_in,
                              void* d_out, int out_size, void* d_ws, size_t ws_size,
                              hipStream_t stream) {
    const float* x  = (const float*)d_in[0];
    const int* ei   = (const int*)d_in[1];   // [2, E] int
    const float* W1 = (const float*)d_in[2];
    const float* b1 = (const float*)d_in[3];
    const float* W2 = (const float*)d_in[4];
    const float* b2 = (const float*)d_in[5];
    float* out = (float*)d_out;

    const int N = N_NODES, E = N_EDGES;
    const int* src = ei;
    const int* dst = ei + E;

    char* ws = (char*)d_ws;
    size_t off = 0;
    auto alloc = [&](size_t bytes) {
        size_t o = off;
        off = (off + bytes + 255) & ~(size_t)255;
        return o;
    };
    _Float16* h16   = (_Float16*)(ws + alloc((size_t)N * C * 2));  // gemm1 out / agg1 in
    _Float16* hB16  = (_Float16*)(ws + alloc((size_t)N * C * 2));  // agg1 out / gemm2 in
    _Float16* hC16  = (_Float16*)(ws + alloc((size_t)N * C * 2));  // gemm2 out / agg2 in
    _Float16* W1s   = (_Float16*)(ws + alloc((size_t)C * C * 2));
    _Float16* W2s   = (_Float16*)(ws + alloc((size_t)C * C * 2));
    int*      cnt   = (int*)     (ws + alloc((size_t)NB * NC * 4)); // count/scan table
    int*      part  = (int*)     (ws + alloc((size_t)1024 * 4));
    unsigned int* bpacked = (unsigned int*)(ws + alloc((size_t)E * 4)); // bucket-sorted packed
    int*      srcs  = (int*)     (ws + alloc((size_t)E * 4));      // node-sorted src list
    int*    rowptr  = (int*)     (ws + alloc((size_t)(N + 1) * 4));
    float*    isq   = (float*)   (ws + alloc((size_t)N * 4));
    (void)ws_size; (void)n_in; (void)in_sizes; (void)out_size;

    const int nbG = (N + 63) / 64;     // 1563
    const int nS  = NB * NC;           // 800768
    const int nbA = N / 16;            // 6250 (exact: 6250*16 == 100000)

    // 1: W swizzle + per-chunk bucket count (LDS histograms, no global atomics)
    init_count<<<16 + NC, 256, 0, stream>>>(W1, W2, W1s, W2s, dst, cnt);

    // 2-3: within-bucket exclusive scan (block b == bucket b) + bucket totals
    scan_block2<<<NB, 1024, 0, stream>>>(cnt, part, nS);
    scan_partial_1024<<<1, 1024, 0, stream>>>(part, NB);

    // 4: gemm layer-1 co-scheduled with 4B bucket scatter (LDS cursors)
    fused_gemm_scatter<<<nbG + NC, 256, 0, stream>>>(x, W1s, h16, N, src, dst, cnt,
                                                     part, bpacked, nbG);

    // 5: per-bucket node sort -> rowptr, isq, node-sorted srcs
    node_sort<<<NB, 256, 0, stream>>>(bpacked, part, srcs, rowptr, isq);

    // 6: layer-1 aggregation + ReLU (fp16 out)
    aggregate<true, _Float16><<<nbA, 256, 0, stream>>>(h16, rowptr, srcs, isq, b1, hB16, N);

    // 7: layer-2 GEMM
    gemm_mfma<<<nbG, 256, 0, stream>>>(hB16, W2s, hC16, N);

    // 8: layer-2 aggregation (fp32 out, +b2)
    aggregate<false, float><<<nbA, 256, 0, stream>>>(hC16, rowptr, srcs, isq, b2, out, N);
}